// Round 1
// 819.279 us; speedup vs baseline: 1.3335x; 1.3335x over previous
//
#include <hip/hip_runtime.h>

#define BATCH 8
#define NROW 4096
#define MCOL 4096
#define DDIM 128
#define RATIO2 0.64f   // 0.8^2
#define DIST2  0.49f   // 0.7^2

typedef __attribute__((ext_vector_type(8))) short bf16x8;
typedef __attribute__((ext_vector_type(4))) float floatx4;

__device__ inline unsigned short f2bf(float f) {
    union { float f; unsigned int u; } v; v.f = f;
    unsigned int r = (v.u + 0x7FFFu + ((v.u >> 16) & 1u)) >> 16;   // RNE
    return (unsigned short)r;
}

// better(candidate v,i vs incumbent v2,i2) with jax top_k tie semantics
// (equal values -> lower index wins). (v,i) is a strict total order since
// indices are unique, so merge order of partial top-2s is irrelevant.
__device__ inline bool better(float v, int i, float v2, int i2) {
    return (v > v2) || (v == v2 && i < i2);
}

struct Top2 { float v1, v2; int i1, i2; };

__device__ inline void t2_insert(Top2& t, float v, int i) {
    if (better(v, i, t.v1, t.i1)) { t.v2 = t.v1; t.i2 = t.i1; t.v1 = v; t.i1 = i; }
    else if (better(v, i, t.v2, t.i2)) { t.v2 = v; t.i2 = i; }
}

__device__ inline void t2_merge(Top2& a, const Top2& b) {
    if (better(b.v1, b.i1, a.v1, a.i1)) {
        float ov = a.v1; int oi = a.i1;
        a.v1 = b.v1; a.i1 = b.i1;
        if (better(b.v2, b.i2, ov, oi)) { a.v2 = b.v2; a.i2 = b.i2; }
        else                            { a.v2 = ov;   a.i2 = oi; }
    } else if (better(b.v1, b.i1, a.v2, a.i2)) {
        a.v2 = b.v1; a.i2 = b.i1;
    }
}

__device__ inline void t2_shfl_merge(Top2& t, int off) {
    Top2 o;
    o.v1 = __shfl_xor(t.v1, off);
    o.v2 = __shfl_xor(t.v2, off);
    o.i1 = __shfl_xor(t.i1, off);
    o.i2 = __shfl_xor(t.i2, off);
    t2_merge(t, o);
}

__device__ inline float4 t2_pack(const Top2& t) {
    return make_float4(t.v1, t.v2, __int_as_float(t.i1), __int_as_float(t.i2));
}
__device__ inline Top2 t2_unpack(float4 p) {
    Top2 t; t.v1 = p.x; t.v2 = p.y; t.i1 = __float_as_int(p.z); t.i2 = __float_as_int(p.w);
    return t;
}

// ---------------- inverse norms ----------------
__global__ void norms_kernel(const float* __restrict__ d0, const float* __restrict__ d1,
                             float* __restrict__ inv0, float* __restrict__ inv1) {
    int row = blockIdx.x * 4 + (threadIdx.x >> 6);
    int lane = threadIdx.x & 63;
    const float* src; float* dst; int r;
    if (row < BATCH * NROW) { src = d0; dst = inv0; r = row; }
    else                    { src = d1; dst = inv1; r = row - BATCH * NROW; }
    float2 v = *(const float2*)&src[(size_t)r * DDIM + lane * 2];
    float ss = v.x * v.x + v.y * v.y;
    #pragma unroll
    for (int off = 32; off > 0; off >>= 1) ss += __shfl_xor(ss, off);
    if (lane == 0) {
        float n = fmaxf(sqrtf(ss), 1e-12f);
        dst[r] = 1.0f / n;
    }
}

// ---------------- bf16 MFMA GEMM fused with per-tile top-2 ----------------
// 128x128 tile per block, K=128 fully resident in LDS.
// LDS layout XOR-swizzled at 16B-chunk granularity (<=2-way conflicts, free).
__device__ inline int lds_off(int row, int k) {
    return row * 128 + (((k >> 3) ^ (row & 7)) << 3) + (k & 7);
}

__global__ __launch_bounds__(256, 2)
void gemm_kernel(const float* __restrict__ d0, const float* __restrict__ d1,
                 const float* __restrict__ inv0, const float* __restrict__ inv1,
                 float* __restrict__ sim,
                 float4* __restrict__ rowPart, float4* __restrict__ colPart) {
    __shared__ unsigned short As[128 * 128];   // 32 KB
    __shared__ unsigned short Bs[128 * 128];   // 32 KB
    __shared__ float4 rowp[128][2];            // 4 KB: per-row top2, per column-half
    __shared__ float4 colp[128][2];            // 4 KB: per-col top2, per row-half
    const int b  = blockIdx.z;
    const int n0 = blockIdx.y * 128;
    const int m0 = blockIdx.x * 128;
    const int tid = threadIdx.x;

    // stage + normalize + cast to bf16
    #pragma unroll
    for (int i = 0; i < 16; ++i) {
        int f  = tid + i * 256;   // float4 slot 0..4095
        int r  = f >> 5;          // tile row
        int k4 = f & 31;          // float4 index along K
        {
            float4 v = *(const float4*)&d0[((size_t)(b * NROW + n0 + r)) * DDIM + k4 * 4];
            float s = inv0[b * NROW + n0 + r];
            ushort4 w;
            w.x = f2bf(v.x * s); w.y = f2bf(v.y * s);
            w.z = f2bf(v.z * s); w.w = f2bf(v.w * s);
            *(ushort4*)&As[lds_off(r, k4 * 4)] = w;
        }
        {
            float4 v = *(const float4*)&d1[((size_t)(b * MCOL + m0 + r)) * DDIM + k4 * 4];
            float s = inv1[b * MCOL + m0 + r];
            ushort4 w;
            w.x = f2bf(v.x * s); w.y = f2bf(v.y * s);
            w.z = f2bf(v.z * s); w.w = f2bf(v.w * s);
            *(ushort4*)&Bs[lds_off(r, k4 * 4)] = w;
        }
    }
    __syncthreads();

    const int wave = tid >> 6;
    const int lane = tid & 63;
    const int quad = lane >> 4;
    const int l15  = lane & 15;
    const int wr = (wave >> 1) * 64;   // wave's 64x64 quadrant
    const int wc = (wave & 1) * 64;

    floatx4 acc[4][4];
    #pragma unroll
    for (int i = 0; i < 4; ++i)
        #pragma unroll
        for (int j = 0; j < 4; ++j)
            acc[i][j] = (floatx4){0.f, 0.f, 0.f, 0.f};

    #pragma unroll
    for (int k0 = 0; k0 < 128; k0 += 32) {
        bf16x8 af[4], bf[4];
        #pragma unroll
        for (int i = 0; i < 4; ++i)
            af[i] = *(const bf16x8*)&As[lds_off(wr + i * 16 + l15, k0 + quad * 8)];
        #pragma unroll
        for (int j = 0; j < 4; ++j)
            bf[j] = *(const bf16x8*)&Bs[lds_off(wc + j * 16 + l15, k0 + quad * 8)];
        #pragma unroll
        for (int i = 0; i < 4; ++i)
            #pragma unroll
            for (int j = 0; j < 4; ++j)
                acc[i][j] = __builtin_amdgcn_mfma_f32_16x16x32_bf16(af[i], bf[j], acc[i][j], 0, 0, 0);
    }

    // C/D layout: col = lane&15, row = quad*4 + reg
    // sim stores (nontemporal: sim is never re-read on-device after fusion)
    #pragma unroll
    for (int i = 0; i < 4; ++i) {
        int n = n0 + wr + i * 16 + quad * 4;
        #pragma unroll
        for (int j = 0; j < 4; ++j) {
            int m = m0 + wc + j * 16 + l15;
            size_t base = ((size_t)(b * NROW + n)) * MCOL + m;
            __builtin_nontemporal_store(acc[i][j][0], &sim[base]);
            __builtin_nontemporal_store(acc[i][j][1], &sim[base + MCOL]);
            __builtin_nontemporal_store(acc[i][j][2], &sim[base + 2 * MCOL]);
            __builtin_nontemporal_store(acc[i][j][3], &sim[base + 3 * MCOL]);
        }
    }

    // ---- row top-2 over this block's 128 cols ----
    // lanes sharing a row differ only in l15; butterfly over l15 bits.
    #pragma unroll
    for (int i = 0; i < 4; ++i) {
        Top2 rt[4];
        #pragma unroll
        for (int r = 0; r < 4; ++r) {
            rt[r].v1 = -2e30f; rt[r].v2 = -2e30f; rt[r].i1 = -1; rt[r].i2 = -1;
            #pragma unroll
            for (int j = 0; j < 4; ++j)
                t2_insert(rt[r], acc[i][j][r], m0 + wc + j * 16 + l15);
        }
        #pragma unroll
        for (int off = 1; off <= 8; off <<= 1)
            #pragma unroll
            for (int r = 0; r < 4; ++r)
                t2_shfl_merge(rt[r], off);
        #pragma unroll
        for (int r = 0; r < 4; ++r)
            if (l15 == i * 4 + r)
                rowp[wr + i * 16 + quad * 4 + r][wave & 1] = t2_pack(rt[r]);
    }

    // ---- col top-2 over this block's 128 rows ----
    // lanes sharing a col differ only in quad; butterfly over quad bits.
    #pragma unroll
    for (int j = 0; j < 4; ++j) {
        Top2 ct;
        ct.v1 = -2e30f; ct.v2 = -2e30f; ct.i1 = -1; ct.i2 = -1;
        #pragma unroll
        for (int i = 0; i < 4; ++i)
            #pragma unroll
            for (int r = 0; r < 4; ++r)
                t2_insert(ct, acc[i][j][r], n0 + wr + i * 16 + quad * 4 + r);
        t2_shfl_merge(ct, 16);
        t2_shfl_merge(ct, 32);
        if (quad == j)
            colp[wc + j * 16 + l15][wave >> 1] = t2_pack(ct);
    }

    __syncthreads();

    // cross-wave merge of the two halves; write per-tile partials.
    // layout rowPart[xt][b*NROW+n], colPart[yt][b*MCOL+m] -> merge kernels read
    // fully coalesced.
    if (tid < 128) {
        Top2 a = t2_unpack(rowp[tid][0]);
        t2_merge(a, t2_unpack(rowp[tid][1]));
        rowPart[(size_t)blockIdx.x * (BATCH * NROW) + b * NROW + n0 + tid] = t2_pack(a);
    } else {
        int c = tid - 128;
        Top2 a = t2_unpack(colp[c][0]);
        t2_merge(a, t2_unpack(colp[c][1]));
        colPart[(size_t)blockIdx.y * (BATCH * MCOL) + b * MCOL + m0 + c] = t2_pack(a);
    }
}

// ---------------- merge 32 per-tile partials per row -> matches0 ----------------
__global__ void row_merge_kernel(const float4* __restrict__ rowPart, int* __restrict__ m0w) {
    int g = blockIdx.x * 256 + threadIdx.x;   // b*NROW + n
    Top2 t; t.v1 = -2e30f; t.v2 = -2e30f; t.i1 = -1; t.i2 = -1;
    #pragma unroll 8
    for (int xt = 0; xt < MCOL / 128; ++xt)
        t2_merge(t, t2_unpack(rowPart[(size_t)xt * (BATCH * NROW) + g]));
    float dd1 = 2.0f * (1.0f - t.v1);
    float dd2 = 2.0f * (1.0f - t.v2);
    bool ok = (dd1 <= RATIO2 * dd2) && (dd1 <= DIST2);
    m0w[g] = ok ? t.i1 : -1;
}

// ---------------- merge 32 per-tile partials per col -> matches1 ----------------
__global__ void col_merge_kernel(const float4* __restrict__ colPart, int* __restrict__ m1w) {
    int g = blockIdx.x * 256 + threadIdx.x;   // b*MCOL + m
    Top2 t; t.v1 = -2e30f; t.v2 = -2e30f; t.i1 = -1; t.i2 = -1;
    #pragma unroll 8
    for (int yt = 0; yt < NROW / 128; ++yt)
        t2_merge(t, t2_unpack(colPart[(size_t)yt * (BATCH * MCOL) + g]));
    float dd1 = 2.0f * (1.0f - t.v1);
    float dd2 = 2.0f * (1.0f - t.v2);
    bool ok = (dd1 <= RATIO2 * dd2) && (dd1 <= DIST2);
    m1w[g] = ok ? t.i1 : -1;
}

// ---------------- mutual check + write small outputs ----------------
__global__ void mutual_kernel(const int* __restrict__ m0w, const int* __restrict__ m1w,
                              float* __restrict__ out) {
    int i = blockIdx.x * 256 + threadIdx.x;   // 0..32767
    int b = i >> 12, x = i & 4095;
    int m0 = m0w[i];
    int r0 = (m0 > -1 && m1w[(b << 12) + m0] == x) ? m0 : -1;
    int m1 = m1w[i];
    int r1 = (m1 > -1 && m0w[(b << 12) + m1] == x) ? m1 : -1;
    out[i]                 = (float)r0;       // matches0
    out[32768 + i]         = (float)r1;       // matches1
    out[65536 + i]         = (r0 > -1) ? 1.0f : 0.0f;   // mscores0
    out[98304 + i]         = (r1 > -1) ? 1.0f : 0.0f;   // mscores1
}

extern "C" void kernel_launch(void* const* d_in, const int* in_sizes, int n_in,
                              void* d_out, int out_size, void* d_ws, size_t ws_size,
                              hipStream_t stream) {
    const float* d0 = (const float*)d_in[0];
    const float* d1 = (const float*)d_in[1];
    float* out = (float*)d_out;
    float* sim = out + 4 * BATCH * NROW;      // sim after the 4 small outputs

    // workspace layout (requires ~33 MB):
    //   inv0/inv1/m0w/m1w : 4 x 128 KB
    //   rowPart           : 32 tiles x 32768 rows x 16 B = 16 MB
    //   colPart           : 32 tiles x 32768 cols x 16 B = 16 MB
    float*  inv0    = (float*)d_ws;                      // 32768
    float*  inv1    = inv0 + BATCH * NROW;               // 32768
    int*    m0w     = (int*)(inv1 + BATCH * MCOL);       // 32768
    int*    m1w     = m0w + BATCH * NROW;                // 32768
    float4* rowPart = (float4*)(m1w + BATCH * MCOL);     // 16 MB (offset 512 KB, 16B-aligned)
    float4* colPart = rowPart + (size_t)(MCOL / 128) * BATCH * NROW;   // 16 MB

    norms_kernel<<<(BATCH * (NROW + MCOL)) / 4, 256, 0, stream>>>(d0, d1, inv0, inv1);
    gemm_kernel<<<dim3(MCOL / 128, NROW / 128, BATCH), 256, 0, stream>>>(
        d0, d1, inv0, inv1, sim, rowPart, colPart);
    row_merge_kernel<<<BATCH * NROW / 256, 256, 0, stream>>>(rowPart, m0w);
    col_merge_kernel<<<BATCH * MCOL / 256, 256, 0, stream>>>(colPart, m1w);
    mutual_kernel<<<BATCH * NROW / 256, 256, 0, stream>>>(m0w, m1w, out);
}

// Round 2
// 613.711 us; speedup vs baseline: 1.7802x; 1.3350x over previous
//
#include <hip/hip_runtime.h>

#define BATCH 8
#define NROW 4096
#define MCOL 4096
#define DDIM 128
#define RATIO2 0.64f   // 0.8^2
#define DIST2  0.49f   // 0.7^2

typedef __attribute__((ext_vector_type(8))) short bf16x8;
typedef __attribute__((ext_vector_type(4))) float floatx4;
typedef unsigned long long u64;

__device__ inline unsigned short f2bf(float f) {
    union { float f; unsigned int u; } v; v.f = f;
    unsigned int r = (v.u + 0x7FFFu + ((v.u >> 16) & 1u)) >> 16;   // RNE
    return (unsigned short)r;
}

// ---- packed sort keys: (monotone(f32) << 32) | ~idx ----
// Total order = (value desc, index asc) — exactly jax top_k tie semantics.
__device__ inline u64 mkkey(float v, unsigned idx) {
    unsigned u = __float_as_uint(v);
    unsigned s = u ^ (0x80000000u | (unsigned)((int)u >> 31));
    return ((u64)s << 32) | (unsigned)(~idx);
}
__device__ inline float keyval(u64 k) {
    unsigned s = (unsigned)(k >> 32);
    unsigned u = ((int)s < 0) ? (s ^ 0x80000000u) : ~s;
    return __uint_as_float(u);
}
__device__ inline int keyidx(u64 k) { return (int)(~(unsigned)k); }

struct KTop2 { u64 k1, k2; };

__device__ inline void k2_insert(KTop2& t, u64 k) {
    bool c1 = k > t.k1;
    bool c2 = k > t.k2;
    u64 old1 = t.k1;
    if (c1) t.k1 = k;
    t.k2 = c1 ? old1 : (c2 ? k : t.k2);
}

// merge (b1,b2) into a; b2 can only ever land in a.k2 (b2 < b1).
__device__ inline void k2_merge(KTop2& a, u64 b1, u64 b2) {
    bool c1 = b1 > a.k1;
    bool c2 = b1 > a.k2;
    u64 old1 = a.k1;
    if (c1) a.k1 = b1;
    a.k2 = c1 ? old1 : (c2 ? b1 : a.k2);
    if (b2 > a.k2) a.k2 = b2;
}

__device__ inline void k2_shfl_merge(KTop2& t, int off) {
    u64 o1 = __shfl_xor(t.k1, off);
    u64 o2 = __shfl_xor(t.k2, off);
    k2_merge(t, o1, o2);
}

// ---------------- normalize + cast to bf16, chunk-swizzled layout ----------------
// element (row, k) stored at row*128 + swz(k>>3, row)*8 + (k&7), where
// swz(c, row) = (c & 8) | ((c & 7) ^ (row & 7)).
// GEMM tiles are 128-row aligned, so tile-local row ≡ global row (mod 8) and
// this global pre-swizzle equals the per-tile LDS swizzle -> GEMM staging is a
// straight linear copy.
__global__ void prep_kernel(const float* __restrict__ d0, const float* __restrict__ d1,
                            unsigned short* __restrict__ d0n, unsigned short* __restrict__ d1n) {
    int row = blockIdx.x * 4 + (threadIdx.x >> 6);
    int lane = threadIdx.x & 63;
    const float* src; unsigned short* dst; int r;
    if (row < BATCH * NROW) { src = d0; dst = d0n; r = row; }
    else                    { src = d1; dst = d1n; r = row - BATCH * NROW; }
    float2 v = *(const float2*)&src[(size_t)r * DDIM + lane * 2];
    float ss = v.x * v.x + v.y * v.y;
    #pragma unroll
    for (int off = 32; off > 0; off >>= 1) ss += __shfl_xor(ss, off);
    float inv = 1.0f / fmaxf(sqrtf(ss), 1e-12f);
    int c  = lane >> 2;                       // 16B chunk 0..15 (both elems same chunk)
    int sc = (c & 8) | ((c & 7) ^ (r & 7));
    int e  = (lane & 3) * 2;
    ushort2 w;
    w.x = f2bf(v.x * inv);
    w.y = f2bf(v.y * inv);
    *(ushort2*)&dst[(size_t)r * DDIM + sc * 8 + e] = w;
}

// ---------------- bf16 MFMA GEMM fused with per-tile top-2 ----------------
// 128x128 tile per block, K=128 fully resident in LDS (pre-swizzled layout).
__device__ inline int lds_off(int row, int k) {
    return row * 128 + (((k >> 3) ^ (row & 7)) << 3) + (k & 7);
}

__global__ __launch_bounds__(256, 2)
void gemm_kernel(const unsigned short* __restrict__ d0n, const unsigned short* __restrict__ d1n,
                 float* __restrict__ sim,
                 ulonglong2* __restrict__ rowPart, ulonglong2* __restrict__ colPart) {
    __shared__ unsigned short As[128 * 128];   // 32 KB
    __shared__ unsigned short Bs[128 * 128];   // 32 KB
    __shared__ ulonglong2 rowp[128][2];        // 4 KB
    __shared__ ulonglong2 colp[128][2];        // 4 KB
    const int b  = blockIdx.z;
    const int n0 = blockIdx.y * 128;
    const int m0 = blockIdx.x * 128;
    const int tid = threadIdx.x;

    // stage: linear 16B copies (input is already normalized/bf16/swizzled)
    {
        const unsigned short* aSrc = d0n + (size_t)(b * NROW + n0) * DDIM;
        const unsigned short* bSrc = d1n + (size_t)(b * MCOL + m0) * DDIM;
        #pragma unroll
        for (int i = 0; i < 8; ++i) {
            int s = tid + i * 256;             // 16B slot 0..2047
            *(uint4*)&As[s * 8] = *(const uint4*)&aSrc[(size_t)s * 8];
            *(uint4*)&Bs[s * 8] = *(const uint4*)&bSrc[(size_t)s * 8];
        }
    }
    __syncthreads();

    const int wave = tid >> 6;
    const int lane = tid & 63;
    const int quad = lane >> 4;
    const int l15  = lane & 15;
    const int wr = (wave >> 1) * 64;   // wave's 64x64 quadrant
    const int wc = (wave & 1) * 64;

    // acc  = A·B^T quadrant: lane holds sim[n=wr+i*16+quad*4+r][m=wc+j*16+l15]
    // accT = B·A^T quadrant: lane holds sim[n=wr+i*16+l15][m=wc+j*16+quad*4+r]
    // (same fragments, operand-swapped MFMA; k-dot is operand-symmetric ->
    //  values bit-identical to acc)
    floatx4 acc[4][4], accT[4][4];
    #pragma unroll
    for (int i = 0; i < 4; ++i)
        #pragma unroll
        for (int j = 0; j < 4; ++j) {
            acc[i][j]  = (floatx4){0.f, 0.f, 0.f, 0.f};
            accT[j][i] = (floatx4){0.f, 0.f, 0.f, 0.f};
        }

    #pragma unroll
    for (int k0 = 0; k0 < 128; k0 += 32) {
        bf16x8 af[4], bf[4];
        #pragma unroll
        for (int i = 0; i < 4; ++i)
            af[i] = *(const bf16x8*)&As[lds_off(wr + i * 16 + l15, k0 + quad * 8)];
        #pragma unroll
        for (int j = 0; j < 4; ++j)
            bf[j] = *(const bf16x8*)&Bs[lds_off(wc + j * 16 + l15, k0 + quad * 8)];
        #pragma unroll
        for (int i = 0; i < 4; ++i)
            #pragma unroll
            for (int j = 0; j < 4; ++j) {
                acc[i][j]  = __builtin_amdgcn_mfma_f32_16x16x32_bf16(af[i], bf[j], acc[i][j], 0, 0, 0);
                accT[j][i] = __builtin_amdgcn_mfma_f32_16x16x32_bf16(bf[j], af[i], accT[j][i], 0, 0, 0);
            }
    }

    // sim stores from acc (nontemporal: never re-read on device)
    #pragma unroll
    for (int i = 0; i < 4; ++i) {
        int n = n0 + wr + i * 16 + quad * 4;
        #pragma unroll
        for (int j = 0; j < 4; ++j) {
            int m = m0 + wc + j * 16 + l15;
            size_t base = ((size_t)(b * NROW + n)) * MCOL + m;
            __builtin_nontemporal_store(acc[i][j][0], &sim[base]);
            __builtin_nontemporal_store(acc[i][j][1], &sim[base + MCOL]);
            __builtin_nontemporal_store(acc[i][j][2], &sim[base + 2 * MCOL]);
            __builtin_nontemporal_store(acc[i][j][3], &sim[base + 3 * MCOL]);
        }
    }

    // ---- row top-2 from accT: row index on l15 -> only quad butterfly ----
    #pragma unroll
    for (int i = 0; i < 4; ++i) {
        KTop2 rt; rt.k1 = 0; rt.k2 = 0;
        #pragma unroll
        for (int j = 0; j < 4; ++j)
            #pragma unroll
            for (int r = 0; r < 4; ++r)
                k2_insert(rt, mkkey(accT[j][i][r], (unsigned)(m0 + wc + j * 16 + quad * 4 + r)));
        k2_shfl_merge(rt, 16);
        k2_shfl_merge(rt, 32);
        if (quad == i)
            rowp[wr + i * 16 + l15][wave & 1] = make_ulonglong2(rt.k1, rt.k2);
    }

    // ---- col top-2 from acc: col index on l15 -> only quad butterfly ----
    #pragma unroll
    for (int j = 0; j < 4; ++j) {
        KTop2 ct; ct.k1 = 0; ct.k2 = 0;
        #pragma unroll
        for (int i = 0; i < 4; ++i)
            #pragma unroll
            for (int r = 0; r < 4; ++r)
                k2_insert(ct, mkkey(acc[i][j][r], (unsigned)(n0 + wr + i * 16 + quad * 4 + r)));
        k2_shfl_merge(ct, 16);
        k2_shfl_merge(ct, 32);
        if (quad == j)
            colp[wc + j * 16 + l15][wave >> 1] = make_ulonglong2(ct.k1, ct.k2);
    }

    __syncthreads();

    // cross-wave merge of the two halves; write per-tile partials (raw keys).
    if (tid < 128) {
        ulonglong2 x = rowp[tid][0], y = rowp[tid][1];
        KTop2 a; a.k1 = x.x; a.k2 = x.y;
        k2_merge(a, y.x, y.y);
        rowPart[(size_t)blockIdx.x * (BATCH * NROW) + b * NROW + n0 + tid] = make_ulonglong2(a.k1, a.k2);
    } else {
        int c = tid - 128;
        ulonglong2 x = colp[c][0], y = colp[c][1];
        KTop2 a; a.k1 = x.x; a.k2 = x.y;
        k2_merge(a, y.x, y.y);
        colPart[(size_t)blockIdx.y * (BATCH * MCOL) + b * MCOL + c + m0] = make_ulonglong2(a.k1, a.k2);
    }
}

// ---------------- merge 32 per-tile partials per row -> matches0 ----------------
__global__ void row_merge_kernel(const ulonglong2* __restrict__ rowPart, int* __restrict__ m0w) {
    int g = blockIdx.x * 256 + threadIdx.x;   // b*NROW + n
    KTop2 t; t.k1 = 0; t.k2 = 0;
    #pragma unroll 8
    for (int xt = 0; xt < MCOL / 128; ++xt) {
        ulonglong2 p = rowPart[(size_t)xt * (BATCH * NROW) + g];
        k2_merge(t, p.x, p.y);
    }
    float v1 = keyval(t.k1), v2 = keyval(t.k2);
    float dd1 = 2.0f * (1.0f - v1);
    float dd2 = 2.0f * (1.0f - v2);
    bool ok = (dd1 <= RATIO2 * dd2) && (dd1 <= DIST2);
    m0w[g] = ok ? keyidx(t.k1) : -1;
}

// ---------------- merge 32 per-tile partials per col -> matches1 ----------------
__global__ void col_merge_kernel(const ulonglong2* __restrict__ colPart, int* __restrict__ m1w) {
    int g = blockIdx.x * 256 + threadIdx.x;   // b*MCOL + m
    KTop2 t; t.k1 = 0; t.k2 = 0;
    #pragma unroll 8
    for (int yt = 0; yt < NROW / 128; ++yt) {
        ulonglong2 p = colPart[(size_t)yt * (BATCH * MCOL) + g];
        k2_merge(t, p.x, p.y);
    }
    float v1 = keyval(t.k1), v2 = keyval(t.k2);
    float dd1 = 2.0f * (1.0f - v1);
    float dd2 = 2.0f * (1.0f - v2);
    bool ok = (dd1 <= RATIO2 * dd2) && (dd1 <= DIST2);
    m1w[g] = ok ? keyidx(t.k1) : -1;
}

// ---------------- mutual check + write small outputs ----------------
__global__ void mutual_kernel(const int* __restrict__ m0w, const int* __restrict__ m1w,
                              float* __restrict__ out) {
    int i = blockIdx.x * 256 + threadIdx.x;   // 0..32767
    int b = i >> 12, x = i & 4095;
    int m0 = m0w[i];
    int r0 = (m0 > -1 && m1w[(b << 12) + m0] == x) ? m0 : -1;
    int m1 = m1w[i];
    int r1 = (m1 > -1 && m0w[(b << 12) + m1] == x) ? m1 : -1;
    out[i]                 = (float)r0;       // matches0
    out[32768 + i]         = (float)r1;       // matches1
    out[65536 + i]         = (r0 > -1) ? 1.0f : 0.0f;   // mscores0
    out[98304 + i]         = (r1 > -1) ? 1.0f : 0.0f;   // mscores1
}

extern "C" void kernel_launch(void* const* d_in, const int* in_sizes, int n_in,
                              void* d_out, int out_size, void* d_ws, size_t ws_size,
                              hipStream_t stream) {
    const float* d0 = (const float*)d_in[0];
    const float* d1 = (const float*)d_in[1];
    float* out = (float*)d_out;
    float* sim = out + 4 * BATCH * NROW;      // sim after the 4 small outputs

    // workspace layout (~57.3 MB):
    //   m0w/m1w : 2 x 128 KB
    //   d0n/d1n : 2 x 8 MB   (normalized bf16, chunk-swizzled)
    //   rowPart : 32 tiles x 32768 rows x 16 B = 16 MB
    //   colPart : 32 tiles x 32768 cols x 16 B = 16 MB
    int* m0w = (int*)d_ws;
    int* m1w = m0w + BATCH * NROW;
    unsigned short* d0n = (unsigned short*)(m1w + BATCH * MCOL);
    unsigned short* d1n = d0n + (size_t)BATCH * NROW * DDIM;
    ulonglong2* rowPart = (ulonglong2*)(d1n + (size_t)BATCH * MCOL * DDIM);
    ulonglong2* colPart = rowPart + (size_t)(MCOL / 128) * BATCH * NROW;

    prep_kernel<<<(BATCH * (NROW + MCOL)) / 4, 256, 0, stream>>>(d0, d1, d0n, d1n);
    gemm_kernel<<<dim3(MCOL / 128, NROW / 128, BATCH), 256, 0, stream>>>(
        d0n, d1n, sim, rowPart, colPart);
    row_merge_kernel<<<BATCH * NROW / 256, 256, 0, stream>>>(rowPart, m0w);
    col_merge_kernel<<<BATCH * MCOL / 256, 256, 0, stream>>>(colPart, m1w);
    mutual_kernel<<<BATCH * NROW / 256, 256, 0, stream>>>(m0w, m1w, out);
}